// Round 1
// baseline (458.848 us; speedup 1.0000x reference)
//
#include <hip/hip_runtime.h>

typedef __bf16 bf16x8 __attribute__((ext_vector_type(8)));
typedef float f32x4 __attribute__((ext_vector_type(4)));

#define DEV __device__ __forceinline__

DEV f32x4 mfma16(bf16x8 a, bf16x8 b, f32x4 c) {
    return __builtin_amdgcn_mfma_f32_16x16x32_bf16(a, b, c, 0, 0, 0);
}

DEV void async16(const void* g, void* l) {
    __builtin_amdgcn_global_load_lds((__attribute__((address_space(1))) void*)g,
                                     (__attribute__((address_space(3))) void*)l, 16, 0, 0);
}

// ---------------- cast x (f32 -> bf16), 8 elems/thread ----------------
__global__ __launch_bounds__(256) void cast_x_kernel(const float4* __restrict__ in,
                                                     bf16x8* __restrict__ out) {
    int i = blockIdx.x * 256 + threadIdx.x;
    float4 a = in[2 * i], b = in[2 * i + 1];
    bf16x8 o;
    o[0] = (__bf16)a.x; o[1] = (__bf16)a.y; o[2] = (__bf16)a.z; o[3] = (__bf16)a.w;
    o[4] = (__bf16)b.x; o[5] = (__bf16)b.y; o[6] = (__bf16)b.z; o[7] = (__bf16)b.w;
    out[i] = o;
}

// ------------- transpose + cast: src (R x C f32) -> dst (C x R bf16) -------------
__global__ void transpose_cast_kernel(const float* __restrict__ src,
                                      __bf16* __restrict__ dst, int R, int C) {
    __shared__ float tile[32][33];
    int tx = threadIdx.x, ty = threadIdx.y;
    int c0 = blockIdx.x * 32, r0 = blockIdx.y * 32;
#pragma unroll
    for (int j = 0; j < 4; ++j)
        tile[ty + j * 8][tx] = src[(size_t)(r0 + ty + j * 8) * C + c0 + tx];
    __syncthreads();
#pragma unroll
    for (int j = 0; j < 4; ++j)
        dst[(size_t)(c0 + ty + j * 8) * R + r0 + tx] = (__bf16)tile[tx][ty + j * 8];
}

// ---------------- GEMM: C[M,N] = A[M,512] * Bt[N,512]^T + bias ----------------
// m97 structure: 128x128 tile, BK=64, global_load_lds(16B), 4 waves of 4x4 16x16 tiles
__global__ __launch_bounds__(256) void gemm_bt(const __bf16* __restrict__ A,
                                               const __bf16* __restrict__ Bt,
                                               const float* __restrict__ bias0,
                                               const float* __restrict__ bias1,
                                               void* __restrict__ Cout, int N, int outF32) {
    __shared__ __bf16 As[128 * 64];
    __shared__ __bf16 Bs[128 * 64];
    const int tid = threadIdx.x;
    const int bm = blockIdx.x, bn = blockIdx.y;
    const int lane = tid & 63, wv = tid >> 6;
    const int quad = lane >> 4, l16 = lane & 15;
    const int wm = (wv & 1) * 64, wn = (wv >> 1) * 64;
    const __bf16* Abase = A + (size_t)bm * 128 * 512;
    const __bf16* Bbase = Bt + (size_t)bn * 128 * 512;
    f32x4 acc[4][4] = {};
    for (int kr = 0; kr < 8; ++kr) {
#pragma unroll
        for (int i = 0; i < 4; ++i) {
            int chunk = i * 256 + tid;
            int r = chunk >> 3, cc = chunk & 7;
            async16(Abase + r * 512 + kr * 64 + cc * 8, &As[chunk * 8]);
            async16(Bbase + r * 512 + kr * 64 + cc * 8, &Bs[chunk * 8]);
        }
        __syncthreads();
#pragma unroll
        for (int kk = 0; kk < 2; ++kk) {
            bf16x8 af[4], bfm[4];
#pragma unroll
            for (int t = 0; t < 4; ++t) {
                af[t]  = *(const bf16x8*)&As[(wm + t * 16 + l16) * 64 + kk * 32 + quad * 8];
                bfm[t] = *(const bf16x8*)&Bs[(wn + t * 16 + l16) * 64 + kk * 32 + quad * 8];
            }
#pragma unroll
            for (int mt = 0; mt < 4; ++mt)
#pragma unroll
                for (int nt = 0; nt < 4; ++nt)
                    acc[mt][nt] = mfma16(af[mt], bfm[nt], acc[mt][nt]);
        }
        __syncthreads();
    }
#pragma unroll
    for (int nt = 0; nt < 4; ++nt) {
        int ng = bn * 128 + wn + nt * 16 + l16;
        float bias = (ng < 512) ? bias0[ng] : bias1[ng - 512];
#pragma unroll
        for (int mt = 0; mt < 4; ++mt) {
#pragma unroll
            for (int r = 0; r < 4; ++r) {
                int mg = bm * 128 + wm + mt * 16 + quad * 4 + r;
                float v = acc[mt][nt][r] + bias;
                if (outF32) ((float*)Cout)[(size_t)mg * N + ng] = v;
                else ((__bf16*)Cout)[(size_t)mg * N + ng] = (__bf16)v;
            }
        }
    }
}

// ---------------- fused window attention, one workgroup per (b, g, nh) ----------------
// DIM=512 NH=16 HEAD=32 WS1=8 WS2=16 SHIFT=4 ; H=W=64, G=32 (gh in [0,8), gw in [0,4))
// N=128 queries, 2N=256 keys (key = roll*128 + ws1*16 + ws2)
#define ATT_SCALE 0.17677669529663687f

__global__ __launch_bounds__(256) void attn_kernel(const __bf16* __restrict__ qkv,
                                                   const float* __restrict__ peq,
                                                   const float* __restrict__ pekv,
                                                   const float* __restrict__ mask,
                                                   __bf16* __restrict__ oatt) {
    // LDS arena: Vt[32][264] | region reused: {Qs[128][40], Ks[256][40]} then Ps[128][264]
    __shared__ __align__(16) char smem[16896 + 67584];
    __bf16* Vt = (__bf16*)smem;                    // [32][264]
    __bf16* Ps = (__bf16*)(smem + 16896);          // [128][264]
    __bf16* Qs = (__bf16*)(smem + 16896);          // [128][40] (overlaps Ps)
    __bf16* Ks = (__bf16*)(smem + 16896 + 10240);  // [256][40]

    const int tid = threadIdx.x;
    const int bid = blockIdx.x;
    const int b = bid >> 9;
    const int g = (bid >> 4) & 31;
    const int nh = bid & 15;
    const int gh = g >> 2, gw = g & 3;
    const int lane = tid & 63, wv = tid >> 6;
    const int quad = lane >> 4, l16 = lane & 15;

    // ---- stage Q with rotary (+ folded 1/sqrt(C) scale) ----
#pragma unroll
    for (int it = 0; it < 8; ++it) {
        int item = it * 256 + tid;
        int n = item >> 4, cp = item & 15;
        int h = gh * 8 + (n >> 4), w = gw * 16 + (n & 15);
        int row = (b * 64 + h) * 64 + w;
        const __bf16* qp = qkv + (size_t)row * 1536 + nh * 32 + 2 * cp;
        float q0 = (float)qp[0], q1 = (float)qp[1];
        int pidx = (g * 128 + n) * 16 + cp;
        float cs = peq[pidx], sn = peq[65536 + pidx];
        Qs[n * 40 + cp]      = (__bf16)((q0 * cs - q1 * sn) * ATT_SCALE);
        Qs[n * 40 + cp + 16] = (__bf16)((q1 * cs + q0 * sn) * ATT_SCALE);
    }
    // ---- stage K with rotary + roll ----
#pragma unroll
    for (int it = 0; it < 16; ++it) {
        int item = it * 256 + tid;
        int ko = item >> 4, cp = item & 15;
        int roll = ko >> 7, n = ko & 127;
        int h = (gh * 8 + (n >> 4) + (roll ? 60 : 4)) & 63;  // roll0: +4, roll1: -4 (mod 64)
        int w = gw * 16 + (n & 15);
        int row = (b * 64 + h) * 64 + w;
        const __bf16* kp = qkv + (size_t)row * 1536 + 512 + nh * 32 + 2 * cp;
        float k0 = (float)kp[0], k1 = (float)kp[1];
        int pidx = (g * 256 + ko) * 16 + cp;
        float cs = pekv[pidx], sn = pekv[131072 + pidx];
        Ks[ko * 40 + cp]      = (__bf16)(k0 * cs - k1 * sn);
        Ks[ko * 40 + cp + 16] = (__bf16)(k1 * cs + k0 * sn);
    }
    // ---- stage V transposed (Vt[ch][key]) ----
#pragma unroll
    for (int it = 0; it < 16; ++it) {
        int item = it * 256 + tid;
        int ko = item >> 4, cp = item & 15;
        int roll = ko >> 7, n = ko & 127;
        int h = (gh * 8 + (n >> 4) + (roll ? 60 : 4)) & 63;
        int w = gw * 16 + (n & 15);
        int row = (b * 64 + h) * 64 + w;
        const __bf16* vp = qkv + (size_t)row * 1536 + 1024 + nh * 32 + 2 * cp;
        Vt[(2 * cp) * 264 + ko]     = vp[0];
        Vt[(2 * cp + 1) * 264 + ko] = vp[1];
    }
    __syncthreads();

    // ---- S = Q K^T : each wave owns 32 query rows x all 256 keys ----
    f32x4 s[2][16];
    {
        f32x4 z = {0.f, 0.f, 0.f, 0.f};
        bf16x8 aq[2];
#pragma unroll
        for (int rt = 0; rt < 2; ++rt)
            aq[rt] = *(const bf16x8*)&Qs[(wv * 32 + rt * 16 + l16) * 40 + quad * 8];
#pragma unroll
        for (int ct = 0; ct < 16; ++ct) {
            bf16x8 bk = *(const bf16x8*)&Ks[(ct * 16 + l16) * 40 + quad * 8];
            s[0][ct] = mfma16(aq[0], bk, z);
            s[1][ct] = mfma16(aq[1], bk, z);
        }
    }
    __syncthreads();  // Qs/Ks reads complete -> Ps region reusable

    // ---- mask add + softmax (f32, in regs) + P -> LDS (bf16, A-layout-friendly) ----
    const float* mg = mask + g * 32768;
#pragma unroll
    for (int rt = 0; rt < 2; ++rt) {
#pragma unroll
        for (int r = 0; r < 4; ++r) {
            int rown = wv * 32 + rt * 16 + quad * 4 + r;
            float mx = -3.0e38f;
#pragma unroll
            for (int ct = 0; ct < 16; ++ct) {
                float v = s[rt][ct][r] + mg[rown * 256 + ct * 16 + l16];
                s[rt][ct][r] = v;
                mx = fmaxf(mx, v);
            }
#pragma unroll
            for (int off = 1; off < 16; off <<= 1)
                mx = fmaxf(mx, __shfl_xor(mx, off));
            float sum = 0.f;
#pragma unroll
            for (int ct = 0; ct < 16; ++ct) {
                float e = __expf(s[rt][ct][r] - mx);
                s[rt][ct][r] = e;
                sum += e;
            }
#pragma unroll
            for (int off = 1; off < 16; off <<= 1)
                sum += __shfl_xor(sum, off);
            float rinv = 1.f / sum;
#pragma unroll
            for (int ct = 0; ct < 16; ++ct)
                Ps[rown * 264 + ct * 16 + l16] = (__bf16)(s[rt][ct][r] * rinv);
        }
    }
    __syncthreads();

    // ---- O = P V ----
    f32x4 o[2][2] = {};
#pragma unroll
    for (int ks = 0; ks < 8; ++ks) {
        bf16x8 a0 = *(const bf16x8*)&Ps[(wv * 32 + l16) * 264 + ks * 32 + quad * 8];
        bf16x8 a1 = *(const bf16x8*)&Ps[(wv * 32 + 16 + l16) * 264 + ks * 32 + quad * 8];
        bf16x8 b0 = *(const bf16x8*)&Vt[l16 * 264 + ks * 32 + quad * 8];
        bf16x8 b1 = *(const bf16x8*)&Vt[(16 + l16) * 264 + ks * 32 + quad * 8];
        o[0][0] = mfma16(a0, b0, o[0][0]);
        o[0][1] = mfma16(a0, b1, o[0][1]);
        o[1][0] = mfma16(a1, b0, o[1][0]);
        o[1][1] = mfma16(a1, b1, o[1][1]);
    }

    // ---- write O straight into (b,h,w, nh*32+c) layout (bf16) ----
#pragma unroll
    for (int rt = 0; rt < 2; ++rt) {
#pragma unroll
        for (int r = 0; r < 4; ++r) {
            int rown = wv * 32 + rt * 16 + quad * 4 + r;
            int h = gh * 8 + (rown >> 4), w = gw * 16 + (rown & 15);
            size_t base = ((size_t)(b * 64 + h) * 64 + w) * 512 + nh * 32;
#pragma unroll
            for (int c2 = 0; c2 < 2; ++c2)
                oatt[base + c2 * 16 + l16] = (__bf16)o[rt][c2][r];
        }
    }
}

extern "C" void kernel_launch(void* const* d_in, const int* in_sizes, int n_in,
                              void* d_out, int out_size, void* d_ws, size_t ws_size,
                              hipStream_t stream) {
    const float* x     = (const float*)d_in[0];
    const float* peq   = (const float*)d_in[1];
    const float* pekv  = (const float*)d_in[2];
    const float* mask  = (const float*)d_in[3];
    const float* wq    = (const float*)d_in[4];
    const float* bq    = (const float*)d_in[5];
    const float* wkv   = (const float*)d_in[6];
    const float* bkv   = (const float*)d_in[7];
    const float* wproj = (const float*)d_in[8];
    const float* bproj = (const float*)d_in[9];
    float* out = (float*)d_out;

    char* ws = (char*)d_ws;
    // workspace layout (bytes):
    //   [0, 33554432)            xb (bf16 32768x512)  -- reused as o_attn after GEMM1
    //   [33554432, 35127296)     wqkvT (bf16 1536x512)
    //   [35127296, 35651584)     wpT   (bf16 512x512)
    //   [35651584, 136314880)    qkv   (bf16 32768x1536)
    __bf16* xb    = (__bf16*)(ws);
    __bf16* oatt  = (__bf16*)(ws);  // overlaps xb (xb dead after GEMM1)
    __bf16* wqkvT = (__bf16*)(ws + 33554432);
    __bf16* wpT   = (__bf16*)(ws + 35127296);
    __bf16* qkv   = (__bf16*)(ws + 35651584);

    cast_x_kernel<<<8192, 256, 0, stream>>>((const float4*)x, (bf16x8*)xb);
    transpose_cast_kernel<<<dim3(16, 16), dim3(32, 8), 0, stream>>>(wq, wqkvT, 512, 512);
    transpose_cast_kernel<<<dim3(32, 16), dim3(32, 8), 0, stream>>>(wkv, wqkvT + 512 * 512, 512, 1024);
    transpose_cast_kernel<<<dim3(16, 16), dim3(32, 8), 0, stream>>>(wproj, wpT, 512, 512);

    gemm_bt<<<dim3(256, 12), 256, 0, stream>>>(xb, wqkvT, bq, bkv, qkv, 1536, 0);
    attn_kernel<<<4096, 256, 0, stream>>>(qkv, peq, pekv, mask, oatt);
    gemm_bt<<<dim3(256, 4), 256, 0, stream>>>(oatt, wpT, bproj, bproj, out, 512, 1);
}

// Round 2
// 449.743 us; speedup vs baseline: 1.0202x; 1.0202x over previous
//
#include <hip/hip_runtime.h>

typedef __bf16 bf16x8 __attribute__((ext_vector_type(8)));
typedef __bf16 bf16x4 __attribute__((ext_vector_type(4)));
typedef float f32x4 __attribute__((ext_vector_type(4)));

#define DEV __device__ __forceinline__

DEV f32x4 mfma16(bf16x8 a, bf16x8 b, f32x4 c) {
    return __builtin_amdgcn_mfma_f32_16x16x32_bf16(a, b, c, 0, 0, 0);
}

DEV void async16(const void* g, void* l) {
    __builtin_amdgcn_global_load_lds((__attribute__((address_space(1))) void*)g,
                                     (__attribute__((address_space(3))) void*)l, 16, 0, 0);
}

// ---------------- cast x (f32 -> bf16), 8 elems/thread ----------------
__global__ __launch_bounds__(256) void cast_x_kernel(const float4* __restrict__ in,
                                                     bf16x8* __restrict__ out) {
    int i = blockIdx.x * 256 + threadIdx.x;
    float4 a = in[2 * i], b = in[2 * i + 1];
    bf16x8 o;
    o[0] = (__bf16)a.x; o[1] = (__bf16)a.y; o[2] = (__bf16)a.z; o[3] = (__bf16)a.w;
    o[4] = (__bf16)b.x; o[5] = (__bf16)b.y; o[6] = (__bf16)b.z; o[7] = (__bf16)b.w;
    out[i] = o;
}

// ------------- transpose + cast: src (R x C f32) -> dst (C x R bf16) -------------
__global__ void transpose_cast_kernel(const float* __restrict__ src,
                                      __bf16* __restrict__ dst, int R, int C) {
    __shared__ float tile[32][33];
    int tx = threadIdx.x, ty = threadIdx.y;
    int c0 = blockIdx.x * 32, r0 = blockIdx.y * 32;
#pragma unroll
    for (int j = 0; j < 4; ++j)
        tile[ty + j * 8][tx] = src[(size_t)(r0 + ty + j * 8) * C + c0 + tx];
    __syncthreads();
#pragma unroll
    for (int j = 0; j < 4; ++j)
        dst[(size_t)(c0 + ty + j * 8) * R + r0 + tx] = (__bf16)tile[tx][ty + j * 8];
}

// ---------------- mask nonzero flags: flags[g] = any(mask[g] != 0) ----------------
__global__ __launch_bounds__(256) void mask_flag_kernel(const float* __restrict__ mask,
                                                        int* __restrict__ flags) {
    int g = blockIdx.x;
    const float4* m4 = (const float4*)(mask + (size_t)g * 32768);
    int any = 0;
    for (int i = threadIdx.x; i < 8192; i += 256) {
        float4 v = m4[i];
        any |= (v.x != 0.f) | (v.y != 0.f) | (v.z != 0.f) | (v.w != 0.f);
    }
    any = __any(any) ? 1 : 0;
    __shared__ int s;
    if (threadIdx.x == 0) s = 0;
    __syncthreads();
    if ((threadIdx.x & 63) == 0 && any) atomicOr(&s, 1);
    __syncthreads();
    if (threadIdx.x == 0) flags[g] = s;
}

// ---------------- GEMM: C[M,N] = A[M,512] * Bt[N,512]^T + bias ----------------
__global__ __launch_bounds__(256) void gemm_bt(const __bf16* __restrict__ A,
                                               const __bf16* __restrict__ Bt,
                                               const float* __restrict__ bias0,
                                               const float* __restrict__ bias1,
                                               void* __restrict__ Cout, int N, int outF32) {
    __shared__ __bf16 As[128 * 64];
    __shared__ __bf16 Bs[128 * 64];
    const int tid = threadIdx.x;
    const int bm = blockIdx.x, bn = blockIdx.y;
    const int lane = tid & 63, wv = tid >> 6;
    const int quad = lane >> 4, l16 = lane & 15;
    const int wm = (wv & 1) * 64, wn = (wv >> 1) * 64;
    const __bf16* Abase = A + (size_t)bm * 128 * 512;
    const __bf16* Bbase = Bt + (size_t)bn * 128 * 512;
    f32x4 acc[4][4] = {};
    for (int kr = 0; kr < 8; ++kr) {
#pragma unroll
        for (int i = 0; i < 4; ++i) {
            int chunk = i * 256 + tid;
            int r = chunk >> 3, cc = chunk & 7;
            async16(Abase + r * 512 + kr * 64 + cc * 8, &As[chunk * 8]);
            async16(Bbase + r * 512 + kr * 64 + cc * 8, &Bs[chunk * 8]);
        }
        __syncthreads();
#pragma unroll
        for (int kk = 0; kk < 2; ++kk) {
            bf16x8 af[4], bfm[4];
#pragma unroll
            for (int t = 0; t < 4; ++t) {
                af[t]  = *(const bf16x8*)&As[(wm + t * 16 + l16) * 64 + kk * 32 + quad * 8];
                bfm[t] = *(const bf16x8*)&Bs[(wn + t * 16 + l16) * 64 + kk * 32 + quad * 8];
            }
#pragma unroll
            for (int mt = 0; mt < 4; ++mt)
#pragma unroll
                for (int nt = 0; nt < 4; ++nt)
                    acc[mt][nt] = mfma16(af[mt], bfm[nt], acc[mt][nt]);
        }
        __syncthreads();
    }
#pragma unroll
    for (int nt = 0; nt < 4; ++nt) {
        int ng = bn * 128 + wn + nt * 16 + l16;
        float bias = (ng < 512) ? bias0[ng] : bias1[ng - 512];
#pragma unroll
        for (int mt = 0; mt < 4; ++mt) {
#pragma unroll
            for (int r = 0; r < 4; ++r) {
                int mg = bm * 128 + wm + mt * 16 + quad * 4 + r;
                float v = acc[mt][nt][r] + bias;
                if (outF32) ((float*)Cout)[(size_t)mg * N + ng] = v;
                else ((__bf16*)Cout)[(size_t)mg * N + ng] = (__bf16)v;
            }
        }
    }
}

// ---------------- fused window attention, one workgroup per (b, g, nh) ----------------
// DIM=512 NH=16 HEAD=32 WS1=8 WS2=16 SHIFT=4 ; H=W=64, G=32 (gh in [0,8), gw in [0,4))
// N=128 queries, 2N=256 keys (key = roll*128 + ws1*16 + ws2)
#define ATT_SCALE 0.17677669529663687f

__global__ __launch_bounds__(256) void attn_kernel(const __bf16* __restrict__ qkv,
                                                   const float* __restrict__ peq,
                                                   const float* __restrict__ pekv,
                                                   const float* __restrict__ mask,
                                                   const int* __restrict__ mflags,
                                                   __bf16* __restrict__ oatt) {
    // LDS arena (46.5 KB -> 3 blocks/CU):
    //   [0, 30720)      Qs[128][40] + Ks[256][40]  -> reused as Ps[128][72] (64-key chunks)
    //   [30720, 47616)  Vt[32][264]
    __shared__ __align__(16) char smem[47616];
    __bf16* Qs = (__bf16*)smem;              // [128][40]
    __bf16* Ks = (__bf16*)(smem + 10240);    // [256][40]
    __bf16* Ps = (__bf16*)smem;              // [128][72], overlaps Qs/Ks after S phase
    __bf16* Vt = (__bf16*)(smem + 30720);    // [32][264]

    const int tid = threadIdx.x;
    const int bid = blockIdx.x;
    const int b = bid >> 9;
    const int g = (bid >> 4) & 31;
    const int nh = bid & 15;
    const int gh = g >> 2, gw = g & 3;
    const int lane = tid & 63, wv = tid >> 6;
    const int quad = lane >> 4, l16 = lane & 15;

    // ---- stage Q with rotary (+ folded 1/sqrt(C) scale), 16B loads ----
#pragma unroll
    for (int it = 0; it < 2; ++it) {
        int item = it * 256 + tid;
        int n = item >> 2, c8 = item & 3;  // 8-channel group
        int h = gh * 8 + (n >> 4), w = gw * 16 + (n & 15);
        int row = (b * 64 + h) * 64 + w;
        bf16x8 v = *(const bf16x8*)(qkv + (size_t)row * 1536 + nh * 32 + c8 * 8);
        int pidx = (g * 128 + n) * 16 + c8 * 4;
        float4 c4 = *(const float4*)(peq + pidx);
        float4 s4 = *(const float4*)(peq + 65536 + pidx);
        float cs[4] = {c4.x, c4.y, c4.z, c4.w}, sn[4] = {s4.x, s4.y, s4.z, s4.w};
        bf16x4 lo, hi;
#pragma unroll
        for (int j = 0; j < 4; ++j) {
            float q0 = (float)v[2 * j], q1 = (float)v[2 * j + 1];
            lo[j] = (__bf16)((q0 * cs[j] - q1 * sn[j]) * ATT_SCALE);
            hi[j] = (__bf16)((q1 * cs[j] + q0 * sn[j]) * ATT_SCALE);
        }
        *(bf16x4*)&Qs[n * 40 + c8 * 4]      = lo;
        *(bf16x4*)&Qs[n * 40 + c8 * 4 + 16] = hi;
    }
    // ---- stage K with rotary + roll, 16B loads ----
#pragma unroll
    for (int it = 0; it < 4; ++it) {
        int item = it * 256 + tid;
        int ko = item >> 2, c8 = item & 3;
        int roll = ko >> 7, n = ko & 127;
        int h = (gh * 8 + (n >> 4) + (roll ? 60 : 4)) & 63;  // roll0: +4, roll1: -4 (mod 64)
        int w = gw * 16 + (n & 15);
        int row = (b * 64 + h) * 64 + w;
        bf16x8 v = *(const bf16x8*)(qkv + (size_t)row * 1536 + 512 + nh * 32 + c8 * 8);
        int pidx = (g * 256 + ko) * 16 + c8 * 4;
        float4 c4 = *(const float4*)(pekv + pidx);
        float4 s4 = *(const float4*)(pekv + 131072 + pidx);
        float cs[4] = {c4.x, c4.y, c4.z, c4.w}, sn[4] = {s4.x, s4.y, s4.z, s4.w};
        bf16x4 lo, hi;
#pragma unroll
        for (int j = 0; j < 4; ++j) {
            float k0 = (float)v[2 * j], k1 = (float)v[2 * j + 1];
            lo[j] = (__bf16)(k0 * cs[j] - k1 * sn[j]);
            hi[j] = (__bf16)(k1 * cs[j] + k0 * sn[j]);
        }
        *(bf16x4*)&Ks[ko * 40 + c8 * 4]      = lo;
        *(bf16x4*)&Ks[ko * 40 + c8 * 4 + 16] = hi;
    }
    // ---- stage V transposed (Vt[ch][key]); wave writes 64 consecutive keys -> no conflicts ----
#pragma unroll
    for (int it = 0; it < 4; ++it) {
        int ko = tid;                      // key
        int roll = ko >> 7, n = ko & 127;
        int h = (gh * 8 + (n >> 4) + (roll ? 60 : 4)) & 63;
        int w = gw * 16 + (n & 15);
        int row = (b * 64 + h) * 64 + w;
        bf16x8 v = *(const bf16x8*)(qkv + (size_t)row * 1536 + 1024 + nh * 32 + it * 8);
#pragma unroll
        for (int j = 0; j < 8; ++j)
            Vt[(it * 8 + j) * 264 + ko] = v[j];
    }
    __syncthreads();

    // ---- S = Q K^T : each wave owns 32 query rows x all 256 keys ----
    f32x4 s[2][16];
    {
        f32x4 z = {0.f, 0.f, 0.f, 0.f};
        bf16x8 aq[2];
#pragma unroll
        for (int rt = 0; rt < 2; ++rt)
            aq[rt] = *(const bf16x8*)&Qs[(wv * 32 + rt * 16 + l16) * 40 + quad * 8];
#pragma unroll
        for (int ct = 0; ct < 16; ++ct) {
            bf16x8 bk = *(const bf16x8*)&Ks[(ct * 16 + l16) * 40 + quad * 8];
            s[0][ct] = mfma16(aq[0], bk, z);
            s[1][ct] = mfma16(aq[1], bk, z);
        }
    }

    // ---- softmax fully in registers (mask gated by per-g nonzero flag) ----
    const bool use_mask = mflags[g] != 0;
    const float* mg = mask + g * 32768;
#pragma unroll
    for (int rt = 0; rt < 2; ++rt) {
#pragma unroll
        for (int r = 0; r < 4; ++r) {
            int rown = wv * 32 + rt * 16 + quad * 4 + r;
            if (use_mask) {
#pragma unroll
                for (int ct = 0; ct < 16; ++ct)
                    s[rt][ct][r] += mg[rown * 256 + ct * 16 + l16];
            }
            float mx = -3.0e38f;
#pragma unroll
            for (int ct = 0; ct < 16; ++ct) mx = fmaxf(mx, s[rt][ct][r]);
#pragma unroll
            for (int off = 1; off < 16; off <<= 1)
                mx = fmaxf(mx, __shfl_xor(mx, off));
            float sum = 0.f;
#pragma unroll
            for (int ct = 0; ct < 16; ++ct) {
                float e = __expf(s[rt][ct][r] - mx);
                s[rt][ct][r] = e;
                sum += e;
            }
#pragma unroll
            for (int off = 1; off < 16; off <<= 1)
                sum += __shfl_xor(sum, off);
            float rinv = 1.f / sum;
#pragma unroll
            for (int ct = 0; ct < 16; ++ct) s[rt][ct][r] *= rinv;
        }
    }

    // ---- O = P V, 64-key chunks through reused LDS region ----
    f32x4 o[2][2] = {};
#pragma unroll
    for (int c = 0; c < 4; ++c) {
        __syncthreads();  // prev chunk's PV reads (or S-phase Qs/Ks reads) complete
#pragma unroll
        for (int rt = 0; rt < 2; ++rt)
#pragma unroll
            for (int r = 0; r < 4; ++r) {
                int rown = wv * 32 + rt * 16 + quad * 4 + r;
#pragma unroll
                for (int cc = 0; cc < 4; ++cc)
                    Ps[rown * 72 + cc * 16 + l16] = (__bf16)s[rt][4 * c + cc][r];
            }
        __syncthreads();
#pragma unroll
        for (int ks2 = 0; ks2 < 2; ++ks2) {
            int ks = c * 2 + ks2;
            bf16x8 a0 = *(const bf16x8*)&Ps[(wv * 32 + l16) * 72 + ks2 * 32 + quad * 8];
            bf16x8 a1 = *(const bf16x8*)&Ps[(wv * 32 + 16 + l16) * 72 + ks2 * 32 + quad * 8];
            bf16x8 b0 = *(const bf16x8*)&Vt[l16 * 264 + ks * 32 + quad * 8];
            bf16x8 b1 = *(const bf16x8*)&Vt[(16 + l16) * 264 + ks * 32 + quad * 8];
            o[0][0] = mfma16(a0, b0, o[0][0]);
            o[0][1] = mfma16(a0, b1, o[0][1]);
            o[1][0] = mfma16(a1, b0, o[1][0]);
            o[1][1] = mfma16(a1, b1, o[1][1]);
        }
    }

    // ---- write O straight into (b,h,w, nh*32+c) layout (bf16) ----
#pragma unroll
    for (int rt = 0; rt < 2; ++rt) {
#pragma unroll
        for (int r = 0; r < 4; ++r) {
            int rown = wv * 32 + rt * 16 + quad * 4 + r;
            int h = gh * 8 + (rown >> 4), w = gw * 16 + (rown & 15);
            size_t base = ((size_t)(b * 64 + h) * 64 + w) * 512 + nh * 32;
#pragma unroll
            for (int c2 = 0; c2 < 2; ++c2)
                oatt[base + c2 * 16 + l16] = (__bf16)o[rt][c2][r];
        }
    }
}

extern "C" void kernel_launch(void* const* d_in, const int* in_sizes, int n_in,
                              void* d_out, int out_size, void* d_ws, size_t ws_size,
                              hipStream_t stream) {
    const float* x     = (const float*)d_in[0];
    const float* peq   = (const float*)d_in[1];
    const float* pekv  = (const float*)d_in[2];
    const float* mask  = (const float*)d_in[3];
    const float* wq    = (const float*)d_in[4];
    const float* bq    = (const float*)d_in[5];
    const float* wkv   = (const float*)d_in[6];
    const float* bkv   = (const float*)d_in[7];
    const float* wproj = (const float*)d_in[8];
    const float* bproj = (const float*)d_in[9];
    float* out = (float*)d_out;

    char* ws = (char*)d_ws;
    // workspace layout (bytes):
    //   [0, 33554432)            xb (bf16 32768x512)  -- reused as o_attn after GEMM1
    //   [33554432, 35127296)     wqkvT (bf16 1536x512) -- first 128B reused as mask flags after GEMM1
    //   [35127296, 35651584)     wpT   (bf16 512x512)
    //   [35651584, 136314880)    qkv   (bf16 32768x1536)
    __bf16* xb    = (__bf16*)(ws);
    __bf16* oatt  = (__bf16*)(ws);  // overlaps xb (xb dead after GEMM1)
    __bf16* wqkvT = (__bf16*)(ws + 33554432);
    int*    mflag = (int*)(ws + 33554432);  // overlaps wqkvT (dead after GEMM1)
    __bf16* wpT   = (__bf16*)(ws + 35127296);
    __bf16* qkv   = (__bf16*)(ws + 35651584);

    cast_x_kernel<<<8192, 256, 0, stream>>>((const float4*)x, (bf16x8*)xb);
    transpose_cast_kernel<<<dim3(16, 16), dim3(32, 8), 0, stream>>>(wq, wqkvT, 512, 512);
    transpose_cast_kernel<<<dim3(32, 16), dim3(32, 8), 0, stream>>>(wkv, wqkvT + 512 * 512, 512, 1024);
    transpose_cast_kernel<<<dim3(16, 16), dim3(32, 8), 0, stream>>>(wproj, wpT, 512, 512);

    gemm_bt<<<dim3(256, 12), 256, 0, stream>>>(xb, wqkvT, bq, bkv, qkv, 1536, 0);
    mask_flag_kernel<<<32, 256, 0, stream>>>(mask, mflag);
    attn_kernel<<<4096, 256, 0, stream>>>(qkv, peq, pekv, mask, mflag, oatt);
    gemm_bt<<<dim3(256, 4), 256, 0, stream>>>(oatt, wpT, bproj, bproj, out, 512, 1);
}

// Round 3
// 354.296 us; speedup vs baseline: 1.2951x; 1.2694x over previous
//
#include <hip/hip_runtime.h>

typedef __bf16 bf16x8 __attribute__((ext_vector_type(8)));
typedef __bf16 bf16x4 __attribute__((ext_vector_type(4)));
typedef float f32x4 __attribute__((ext_vector_type(4)));

#define DEV __device__ __forceinline__

DEV f32x4 mfma16(bf16x8 a, bf16x8 b, f32x4 c) {
    return __builtin_amdgcn_mfma_f32_16x16x32_bf16(a, b, c, 0, 0, 0);
}

DEV void async16(const void* g, void* l) {
    __builtin_amdgcn_global_load_lds((__attribute__((address_space(1))) void*)g,
                                     (__attribute__((address_space(3))) void*)l, 16, 0, 0);
}

// compiler-only ordering fence (no instruction emitted)
#define LDS_FENCE() asm volatile("" ::: "memory")

// ---------------- cast x (f32 -> bf16), 8 elems/thread ----------------
__global__ __launch_bounds__(256) void cast_x_kernel(const float4* __restrict__ in,
                                                     bf16x8* __restrict__ out) {
    int i = blockIdx.x * 256 + threadIdx.x;
    float4 a = in[2 * i], b = in[2 * i + 1];
    bf16x8 o;
    o[0] = (__bf16)a.x; o[1] = (__bf16)a.y; o[2] = (__bf16)a.z; o[3] = (__bf16)a.w;
    o[4] = (__bf16)b.x; o[5] = (__bf16)b.y; o[6] = (__bf16)b.z; o[7] = (__bf16)b.w;
    out[i] = o;
}

// ------------- transpose + cast: src (R x C f32) -> dst (C x R bf16) -------------
__global__ void transpose_cast_kernel(const float* __restrict__ src,
                                      __bf16* __restrict__ dst, int R, int C) {
    __shared__ float tile[32][33];
    int tx = threadIdx.x, ty = threadIdx.y;
    int c0 = blockIdx.x * 32, r0 = blockIdx.y * 32;
#pragma unroll
    for (int j = 0; j < 4; ++j)
        tile[ty + j * 8][tx] = src[(size_t)(r0 + ty + j * 8) * C + c0 + tx];
    __syncthreads();
#pragma unroll
    for (int j = 0; j < 4; ++j)
        dst[(size_t)(c0 + ty + j * 8) * R + r0 + tx] = (__bf16)tile[tx][ty + j * 8];
}

// ---------------- mask nonzero flags: flags[g] = any(mask[g] != 0) ----------------
__global__ __launch_bounds__(256) void mask_flag_kernel(const float* __restrict__ mask,
                                                        int* __restrict__ flags) {
    int g = blockIdx.x;
    const float4* m4 = (const float4*)(mask + (size_t)g * 32768);
    int any = 0;
    for (int i = threadIdx.x; i < 8192; i += 256) {
        float4 v = m4[i];
        any |= (v.x != 0.f) | (v.y != 0.f) | (v.z != 0.f) | (v.w != 0.f);
    }
    any = __any(any) ? 1 : 0;
    __shared__ int s;
    if (threadIdx.x == 0) s = 0;
    __syncthreads();
    if ((threadIdx.x & 63) == 0 && any) atomicOr(&s, 1);
    __syncthreads();
    if (threadIdx.x == 0) flags[g] = s;
}

// ---------------- GEMM: C[M,N] = A[M,512] * Bt[N,512]^T + bias ----------------
__global__ __launch_bounds__(256) void gemm_bt(const __bf16* __restrict__ A,
                                               const __bf16* __restrict__ Bt,
                                               const float* __restrict__ bias0,
                                               const float* __restrict__ bias1,
                                               void* __restrict__ Cout, int N, int outF32) {
    __shared__ __bf16 As[128 * 64];
    __shared__ __bf16 Bs[128 * 64];
    const int tid = threadIdx.x;
    const int bm = blockIdx.x, bn = blockIdx.y;
    const int lane = tid & 63, wv = tid >> 6;
    const int quad = lane >> 4, l16 = lane & 15;
    const int wm = (wv & 1) * 64, wn = (wv >> 1) * 64;
    const __bf16* Abase = A + (size_t)bm * 128 * 512;
    const __bf16* Bbase = Bt + (size_t)bn * 128 * 512;
    f32x4 acc[4][4] = {};
    for (int kr = 0; kr < 8; ++kr) {
#pragma unroll
        for (int i = 0; i < 4; ++i) {
            int chunk = i * 256 + tid;
            int r = chunk >> 3, cc = chunk & 7;
            async16(Abase + r * 512 + kr * 64 + cc * 8, &As[chunk * 8]);
            async16(Bbase + r * 512 + kr * 64 + cc * 8, &Bs[chunk * 8]);
        }
        __syncthreads();
#pragma unroll
        for (int kk = 0; kk < 2; ++kk) {
            bf16x8 af[4], bfm[4];
#pragma unroll
            for (int t = 0; t < 4; ++t) {
                af[t]  = *(const bf16x8*)&As[(wm + t * 16 + l16) * 64 + kk * 32 + quad * 8];
                bfm[t] = *(const bf16x8*)&Bs[(wn + t * 16 + l16) * 64 + kk * 32 + quad * 8];
            }
#pragma unroll
            for (int mt = 0; mt < 4; ++mt)
#pragma unroll
                for (int nt = 0; nt < 4; ++nt)
                    acc[mt][nt] = mfma16(af[mt], bfm[nt], acc[mt][nt]);
        }
        __syncthreads();
    }
#pragma unroll
    for (int nt = 0; nt < 4; ++nt) {
        int ng = bn * 128 + wn + nt * 16 + l16;
        float bias = (ng < 512) ? bias0[ng] : bias1[ng - 512];
#pragma unroll
        for (int mt = 0; mt < 4; ++mt) {
#pragma unroll
            for (int r = 0; r < 4; ++r) {
                int mg = bm * 128 + wm + mt * 16 + quad * 4 + r;
                float v = acc[mt][nt][r] + bias;
                if (outF32) ((float*)Cout)[(size_t)mg * N + ng] = v;
                else ((__bf16*)Cout)[(size_t)mg * N + ng] = (__bf16)v;
            }
        }
    }
}

// ---------------- fused window attention, one workgroup per (b, g, nh) ----------------
// DIM=512 NH=16 HEAD=32 WS1=8 WS2=16 SHIFT=4 ; H=W=64, G=32 (gh in [0,8), gw in [0,4))
// N=128 queries, 2N=256 keys (key = roll*128 + ws1*16 + ws2)
// v3: Q in registers; K swizzled unpadded; per-wave private P slices; 1 barrier total;
//     8x32-key flash chunks, no max-subtraction (cancels exactly); VGPR<=128 (4 blk/CU).
#define ATT_SCALE 0.17677669529663687f

__global__ __launch_bounds__(256, 4) void attn_kernel(const __bf16* __restrict__ qkv,
                                                      const float* __restrict__ peq,
                                                      const float* __restrict__ pekv,
                                                      const float* __restrict__ mask,
                                                      const int* __restrict__ mflags,
                                                      __bf16* __restrict__ oatt) {
    // LDS 38400 B -> 4 blocks/CU:
    //   [0,16384)      Ks: swizzled [256 keys][32 ch], chunk p = c ^ ((key>>1)&3)
    //   [16384,33280)  Vt[32][264]
    //   [33280,38400)  Ps: 4 per-wave slices of [16 rows][40]
    __shared__ __align__(16) char smem[38400];
    __bf16* Ks = (__bf16*)smem;
    __bf16* Vt = (__bf16*)(smem + 16384);
    __bf16* Ps = (__bf16*)(smem + 33280);

    const int tid = threadIdx.x;
    // XCD swizzle: 16 nh-siblings (same qkv rows) -> same XCD; XCD x <- batch x
    const int bid = ((blockIdx.x & 7) << 9) | (blockIdx.x >> 3);
    const int b = bid >> 9;
    const int g = (bid >> 4) & 31;
    const int nh = bid & 15;
    const int gh = g >> 2, gw = g & 3;
    const int lane = tid & 63, wv = tid >> 6;
    const int quad = lane >> 4, l16 = lane & 15;

    // ---- stage K with rotary + roll into swizzled layout ----
#pragma unroll
    for (int it = 0; it < 4; ++it) {
        int item = it * 256 + tid;
        int ko = item >> 2, c8 = item & 3;
        int roll = ko >> 7, n = ko & 127;
        int h = (gh * 8 + (n >> 4) + (roll ? 60 : 4)) & 63;  // roll0:+4, roll1:-4 (mod 64)
        int w = gw * 16 + (n & 15);
        int row = (b * 64 + h) * 64 + w;
        bf16x8 v = *(const bf16x8*)(qkv + (size_t)row * 1536 + 512 + nh * 32 + c8 * 8);
        int pidx = (g * 256 + ko) * 16 + c8 * 4;
        float4 c4 = *(const float4*)(pekv + pidx);
        float4 s4 = *(const float4*)(pekv + 131072 + pidx);
        float cs[4] = {c4.x, c4.y, c4.z, c4.w}, sn[4] = {s4.x, s4.y, s4.z, s4.w};
        bf16x4 lo, hi;
#pragma unroll
        for (int j = 0; j < 4; ++j) {
            float k0 = (float)v[2 * j], k1 = (float)v[2 * j + 1];
            lo[j] = (__bf16)(k0 * cs[j] - k1 * sn[j]);
            hi[j] = (__bf16)(k1 * cs[j] + k0 * sn[j]);
        }
        int sw = (ko >> 1) & 3;
        int base = ko * 32, off = (c8 & 1) * 4;
        *(bf16x4*)&Ks[base + (((c8 >> 1) ^ sw) << 3) + off]       = lo;
        *(bf16x4*)&Ks[base + (((2 + (c8 >> 1)) ^ sw) << 3) + off] = hi;
    }
    // ---- stage V transposed (Vt[ch][key]) ----
#pragma unroll
    for (int it = 0; it < 4; ++it) {
        int ko = tid;
        int roll = ko >> 7, n = ko & 127;
        int h = (gh * 8 + (n >> 4) + (roll ? 60 : 4)) & 63;
        int w = gw * 16 + (n & 15);
        int row = (b * 64 + h) * 64 + w;
        bf16x8 v = *(const bf16x8*)(qkv + (size_t)row * 1536 + 1024 + nh * 32 + it * 8);
#pragma unroll
        for (int j = 0; j < 8; ++j)
            Vt[(it * 8 + j) * 264 + ko] = v[j];
    }

    // ---- Q A-fragments straight into registers (overlaps staging latency) ----
    bf16x8 aq[2];
    {
        const int halfsel = quad & 1;      // raw channel half
        const bool hi_half = quad >= 2;    // rotary output half
#pragma unroll
        for (int rt = 0; rt < 2; ++rt) {
            int n = wv * 32 + rt * 16 + l16;
            int h = gh * 8 + (n >> 4), w = gw * 16 + (n & 15);
            int row = (b * 64 + h) * 64 + w;
            const __bf16* qp = qkv + (size_t)row * 1536 + nh * 32 + halfsel * 16;
            bf16x8 rA = *(const bf16x8*)qp;
            bf16x8 rB = *(const bf16x8*)(qp + 8);
            int pb = (g * 128 + n) * 16 + halfsel * 8;
            float4 ca = *(const float4*)(peq + pb);
            float4 cb = *(const float4*)(peq + pb + 4);
            float4 sa = *(const float4*)(peq + 65536 + pb);
            float4 sb = *(const float4*)(peq + 65536 + pb + 4);
            float cc[8] = {ca.x, ca.y, ca.z, ca.w, cb.x, cb.y, cb.z, cb.w};
            float ss[8] = {sa.x, sa.y, sa.z, sa.w, sb.x, sb.y, sb.z, sb.w};
#pragma unroll
            for (int j = 0; j < 8; ++j) {
                float q0 = (float)(j < 4 ? rA[2 * j] : rB[2 * (j - 4)]);
                float q1 = (float)(j < 4 ? rA[2 * j + 1] : rB[2 * (j - 4) + 1]);
                float r = hi_half ? (q1 * cc[j] + q0 * ss[j]) : (q0 * cc[j] - q1 * ss[j]);
                aq[rt][j] = (__bf16)(r * ATT_SCALE);
            }
        }
    }
    __syncthreads();  // the ONLY barrier

    // ---- barrier-free flash loop: 8 chunks x 32 keys ----
    f32x4 o00 = {}, o01 = {}, o10 = {}, o11 = {};
    f32x4 rs0 = {}, rs1 = {};
    const bool use_mask = mflags[g] != 0;
    const float* mg = mask + (size_t)g * 32768;
    __bf16* Pw = Ps + wv * 640;           // private [16][40] slice
    const int arow = l16 * 40 + quad * 8; // A-frag read address (elems)

#pragma unroll 2
    for (int ch = 0; ch < 8; ++ch) {
        bf16x8 vb0 = *(const bf16x8*)&Vt[l16 * 264 + ch * 32 + quad * 8];
        bf16x8 vb1 = *(const bf16x8*)&Vt[(16 + l16) * 264 + ch * 32 + quad * 8];
        f32x4 z = {0.f, 0.f, 0.f, 0.f};
        int key0 = ch * 32 + l16, key1 = key0 + 16;
        bf16x8 bk0 = *(const bf16x8*)&Ks[key0 * 32 + ((quad ^ ((key0 >> 1) & 3)) << 3)];
        bf16x8 bk1 = *(const bf16x8*)&Ks[key1 * 32 + ((quad ^ ((key1 >> 1) & 3)) << 3)];
        f32x4 s00 = mfma16(aq[0], bk0, z), s01 = mfma16(aq[0], bk1, z);
        f32x4 s10 = mfma16(aq[1], bk0, z), s11 = mfma16(aq[1], bk1, z);

        if (use_mask) {
#pragma unroll
            for (int r = 0; r < 4; ++r) {
                int r0 = (wv * 32 + quad * 4 + r) * 256 + ch * 32 + l16;
                int r1 = (wv * 32 + 16 + quad * 4 + r) * 256 + ch * 32 + l16;
                s00[r] += mg[r0];      s01[r] += mg[r0 + 16];
                s10[r] += mg[r1];      s11[r] += mg[r1 + 16];
            }
        }
#pragma unroll
        for (int r = 0; r < 4; ++r) {
            s00[r] = __expf(s00[r]); s01[r] = __expf(s01[r]);
            s10[r] = __expf(s10[r]); s11[r] = __expf(s11[r]);
            rs0[r] += s00[r] + s01[r];
            rs1[r] += s10[r] + s11[r];
        }
        // P(rt0) -> own slice -> A-frag; in-order DS pipe makes this safe barrier-free
#pragma unroll
        for (int r = 0; r < 4; ++r) {
            Pw[(quad * 4 + r) * 40 + l16]      = (__bf16)s00[r];
            Pw[(quad * 4 + r) * 40 + 16 + l16] = (__bf16)s01[r];
        }
        LDS_FENCE();
        bf16x8 a0 = *(const bf16x8*)&Pw[arow];
        LDS_FENCE();
#pragma unroll
        for (int r = 0; r < 4; ++r) {
            Pw[(quad * 4 + r) * 40 + l16]      = (__bf16)s10[r];
            Pw[(quad * 4 + r) * 40 + 16 + l16] = (__bf16)s11[r];
        }
        LDS_FENCE();
        bf16x8 a1 = *(const bf16x8*)&Pw[arow];
        LDS_FENCE();
        o00 = mfma16(a0, vb0, o00); o01 = mfma16(a0, vb1, o01);
        o10 = mfma16(a1, vb0, o10); o11 = mfma16(a1, vb1, o11);
    }

    // ---- finish row sums (16-lane butterfly) and normalize ----
#pragma unroll
    for (int off = 1; off < 16; off <<= 1) {
#pragma unroll
        for (int r = 0; r < 4; ++r) {
            rs0[r] += __shfl_xor(rs0[r], off);
            rs1[r] += __shfl_xor(rs1[r], off);
        }
    }
#pragma unroll
    for (int r = 0; r < 4; ++r) { rs0[r] = 1.f / rs0[r]; rs1[r] = 1.f / rs1[r]; }

    // ---- write O straight into (b,h,w, nh*32+c) layout (bf16) ----
#pragma unroll
    for (int r = 0; r < 4; ++r) {
        {
            int rown = wv * 32 + quad * 4 + r;
            int h = gh * 8 + (rown >> 4), w = gw * 16 + (rown & 15);
            size_t base = ((size_t)(b * 64 + h) * 64 + w) * 512 + nh * 32;
            oatt[base + l16]      = (__bf16)(o00[r] * rs0[r]);
            oatt[base + 16 + l16] = (__bf16)(o01[r] * rs0[r]);
        }
        {
            int rown = wv * 32 + 16 + quad * 4 + r;
            int h = gh * 8 + (rown >> 4), w = gw * 16 + (rown & 15);
            size_t base = ((size_t)(b * 64 + h) * 64 + w) * 512 + nh * 32;
            oatt[base + l16]      = (__bf16)(o10[r] * rs1[r]);
            oatt[base + 16 + l16] = (__bf16)(o11[r] * rs1[r]);
        }
    }
}

extern "C" void kernel_launch(void* const* d_in, const int* in_sizes, int n_in,
                              void* d_out, int out_size, void* d_ws, size_t ws_size,
                              hipStream_t stream) {
    const float* x     = (const float*)d_in[0];
    const float* peq   = (const float*)d_in[1];
    const float* pekv  = (const float*)d_in[2];
    const float* mask  = (const float*)d_in[3];
    const float* wq    = (const float*)d_in[4];
    const float* bq    = (const float*)d_in[5];
    const float* wkv   = (const float*)d_in[6];
    const float* bkv   = (const float*)d_in[7];
    const float* wproj = (const float*)d_in[8];
    const float* bproj = (const float*)d_in[9];
    float* out = (float*)d_out;

    char* ws = (char*)d_ws;
    // workspace layout (bytes):
    //   [0, 33554432)            xb (bf16 32768x512)  -- reused as o_attn after GEMM1
    //   [33554432, 35127296)     wqkvT (bf16 1536x512) -- reused as mask flags after GEMM1
    //   [35127296, 35651584)     wpT   (bf16 512x512)
    //   [35651584, 136314880)    qkv   (bf16 32768x1536)
    __bf16* xb    = (__bf16*)(ws);
    __bf16* oatt  = (__bf16*)(ws);
    __bf16* wqkvT = (__bf16*)(ws + 33554432);
    int*    mflag = (int*)(ws + 33554432);
    __bf16* wpT   = (__bf16*)(ws + 35127296);
    __bf16* qkv   = (__bf16*)(ws + 35651584);

    cast_x_kernel<<<8192, 256, 0, stream>>>((const float4*)x, (bf16x8*)xb);
    transpose_cast_kernel<<<dim3(16, 16), dim3(32, 8), 0, stream>>>(wq, wqkvT, 512, 512);
    transpose_cast_kernel<<<dim3(32, 16), dim3(32, 8), 0, stream>>>(wkv, wqkvT + 512 * 512, 512, 1024);
    transpose_cast_kernel<<<dim3(16, 16), dim3(32, 8), 0, stream>>>(wproj, wpT, 512, 512);

    gemm_bt<<<dim3(256, 12), 256, 0, stream>>>(xb, wqkvT, bq, bkv, qkv, 1536, 0);
    mask_flag_kernel<<<32, 256, 0, stream>>>(mask, mflag);
    attn_kernel<<<4096, 256, 0, stream>>>(qkv, peq, pekv, mask, mflag, oatt);
    gemm_bt<<<dim3(256, 4), 256, 0, stream>>>(oatt, wpT, bproj, bproj, out, 512, 1);
}

// Round 4
// 324.845 us; speedup vs baseline: 1.4125x; 1.0907x over previous
//
#include <hip/hip_runtime.h>

typedef __bf16 bf16x8 __attribute__((ext_vector_type(8)));
typedef __bf16 bf16x4 __attribute__((ext_vector_type(4)));
typedef float f32x4 __attribute__((ext_vector_type(4)));

#define DEV __device__ __forceinline__

DEV f32x4 mfma16(bf16x8 a, bf16x8 b, f32x4 c) {
    return __builtin_amdgcn_mfma_f32_16x16x32_bf16(a, b, c, 0, 0, 0);
}

DEV void async16(const void* g, void* l) {
    __builtin_amdgcn_global_load_lds((__attribute__((address_space(1))) void*)g,
                                     (__attribute__((address_space(3))) void*)l, 16, 0, 0);
}

// compiler-only ordering fence (no instruction emitted)
#define LDS_FENCE() asm volatile("" ::: "memory")

// ---------------- cast x (f32 -> bf16), 8 elems/thread ----------------
__global__ __launch_bounds__(256) void cast_x_kernel(const float4* __restrict__ in,
                                                     bf16x8* __restrict__ out) {
    int i = blockIdx.x * 256 + threadIdx.x;
    float4 a = in[2 * i], b = in[2 * i + 1];
    bf16x8 o;
    o[0] = (__bf16)a.x; o[1] = (__bf16)a.y; o[2] = (__bf16)a.z; o[3] = (__bf16)a.w;
    o[4] = (__bf16)b.x; o[5] = (__bf16)b.y; o[6] = (__bf16)b.z; o[7] = (__bf16)b.w;
    out[i] = o;
}

// ------------- transpose + cast: src (R x C f32) -> dst (C x R bf16) -------------
__global__ void transpose_cast_kernel(const float* __restrict__ src,
                                      __bf16* __restrict__ dst, int R, int C) {
    __shared__ float tile[32][33];
    int tx = threadIdx.x, ty = threadIdx.y;
    int c0 = blockIdx.x * 32, r0 = blockIdx.y * 32;
#pragma unroll
    for (int j = 0; j < 4; ++j)
        tile[ty + j * 8][tx] = src[(size_t)(r0 + ty + j * 8) * C + c0 + tx];
    __syncthreads();
#pragma unroll
    for (int j = 0; j < 4; ++j)
        dst[(size_t)(c0 + ty + j * 8) * R + r0 + tx] = (__bf16)tile[tx][ty + j * 8];
}

// ---------------- mask nonzero flags: flags[g] = any(mask[g] != 0) ----------------
__global__ __launch_bounds__(256) void mask_flag_kernel(const float* __restrict__ mask,
                                                        int* __restrict__ flags) {
    int g = blockIdx.x;
    const float4* m4 = (const float4*)(mask + (size_t)g * 32768);
    int any = 0;
    for (int i = threadIdx.x; i < 8192; i += 256) {
        float4 v = m4[i];
        any |= (v.x != 0.f) | (v.y != 0.f) | (v.z != 0.f) | (v.w != 0.f);
    }
    any = __any(any) ? 1 : 0;
    __shared__ int s;
    if (threadIdx.x == 0) s = 0;
    __syncthreads();
    if ((threadIdx.x & 63) == 0 && any) atomicOr(&s, 1);
    __syncthreads();
    if (threadIdx.x == 0) flags[g] = s;
}

// ---------------- GEMM: C = A[M,512] * Bt[N,512]^T + bias ----------------
// LDS tiles XOR-swizzled: physical 16B chunk p = c ^ (row & 7); the permutation is
// applied on the GLOBAL source address (LDS dest of global_load_lds must stay
// base + lane*16), within each row's 128B span -> coalescing unchanged.
// mode 0: write bf16 qkv relayout [type][nh][32768][32]   (N=1536)
// mode 1: write f32 row-major C[M][N]
__global__ __launch_bounds__(256) void gemm_bt(const __bf16* __restrict__ A,
                                               const __bf16* __restrict__ Bt,
                                               const float* __restrict__ bias0,
                                               const float* __restrict__ bias1,
                                               void* __restrict__ Cout, int N, int mode) {
    __shared__ __bf16 As[128 * 64];
    __shared__ __bf16 Bs[128 * 64];
    const int tid = threadIdx.x;
    const int bm = blockIdx.x, bn = blockIdx.y;
    const int lane = tid & 63, wv = tid >> 6;
    const int quad = lane >> 4, l16 = lane & 15;
    const int wm = (wv & 1) * 64, wn = (wv >> 1) * 64;
    const __bf16* Abase = A + (size_t)bm * 128 * 512;
    const __bf16* Bbase = Bt + (size_t)bn * 128 * 512;
    f32x4 acc[4][4] = {};
    for (int kr = 0; kr < 8; ++kr) {
#pragma unroll
        for (int i = 0; i < 4; ++i) {
            int chunk = i * 256 + tid;
            int r = chunk >> 3, cc = chunk & 7;
            int src = cc ^ (r & 7);  // inverse of the involutive XOR layout
            async16(Abase + r * 512 + kr * 64 + src * 8, &As[chunk * 8]);
            async16(Bbase + r * 512 + kr * 64 + src * 8, &Bs[chunk * 8]);
        }
        __syncthreads();
#pragma unroll
        for (int kk = 0; kk < 2; ++kk) {
            bf16x8 af[4], bfm[4];
#pragma unroll
            for (int t = 0; t < 4; ++t) {
                int ra = wm + t * 16 + l16, rb = wn + t * 16 + l16;
                int c = kk * 4 + quad;
                af[t]  = *(const bf16x8*)&As[ra * 64 + ((c ^ (ra & 7)) << 3)];
                bfm[t] = *(const bf16x8*)&Bs[rb * 64 + ((c ^ (rb & 7)) << 3)];
            }
#pragma unroll
            for (int mt = 0; mt < 4; ++mt)
#pragma unroll
                for (int nt = 0; nt < 4; ++nt)
                    acc[mt][nt] = mfma16(af[mt], bfm[nt], acc[mt][nt]);
        }
        __syncthreads();
    }
#pragma unroll
    for (int nt = 0; nt < 4; ++nt) {
        int ng = bn * 128 + wn + nt * 16 + l16;
        float bias = (ng < 512) ? bias0[ng] : bias1[ng - 512];
        if (mode == 0) {
            int type = ng >> 9, nhh = (ng >> 5) & 15, c = ng & 31;
            __bf16* dst = (__bf16*)Cout + (size_t)type * 16777216 + (size_t)nhh * 1048576 + c;
#pragma unroll
            for (int mt = 0; mt < 4; ++mt)
#pragma unroll
                for (int r = 0; r < 4; ++r) {
                    int mg = bm * 128 + wm + mt * 16 + quad * 4 + r;
                    dst[(size_t)mg * 32] = (__bf16)(acc[mt][nt][r] + bias);
                }
        } else {
#pragma unroll
            for (int mt = 0; mt < 4; ++mt)
#pragma unroll
                for (int r = 0; r < 4; ++r) {
                    int mg = bm * 128 + wm + mt * 16 + quad * 4 + r;
                    ((float*)Cout)[(size_t)mg * N + ng] = acc[mt][nt][r] + bias;
                }
        }
    }
}

// ---------------- fused window attention, one workgroup per (b, g, nh) ----------------
// qkv layout: [type(q/k/v)][nh][row = (b*64+h)*64+w][32 ch]  (bf16)
// N=128 queries, 2N=256 keys (key = roll*128 + ws1*16 + ws2)
#define ATT_SCALE 0.17677669529663687f

__global__ __launch_bounds__(256, 4) void attn_kernel(const __bf16* __restrict__ qkv,
                                                      const float* __restrict__ peq,
                                                      const float* __restrict__ pekv,
                                                      const float* __restrict__ mask,
                                                      const int* __restrict__ mflags,
                                                      __bf16* __restrict__ oatt) {
    // LDS 38400 B -> 4 blocks/CU:
    //   [0,16384)      Ks: swizzled [256 keys][32 ch], chunk p = c ^ ((key>>1)&3)
    //   [16384,33280)  Vt[32][264]
    //   [33280,38400)  Ps: 4 per-wave slices of [16 rows][40]
    __shared__ __align__(16) char smem[38400];
    __bf16* Ks = (__bf16*)smem;
    __bf16* Vt = (__bf16*)(smem + 16384);
    __bf16* Ps = (__bf16*)(smem + 33280);

    const int tid = threadIdx.x;
    // XCD swizzle: 16 nh-siblings (same qkv rows) -> same XCD; XCD x <- batch x
    const int bid = ((blockIdx.x & 7) << 9) | (blockIdx.x >> 3);
    const int b = bid >> 9;
    const int g = (bid >> 4) & 31;
    const int nh = bid & 15;
    const int gh = g >> 2, gw = g & 3;
    const int lane = tid & 63, wv = tid >> 6;
    const int quad = lane >> 4, l16 = lane & 15;

    const __bf16* qq = qkv + (size_t)nh * 1048576;
    const __bf16* kkp = qkv + 16777216 + (size_t)nh * 1048576;
    const __bf16* vvp = qkv + 33554432 + (size_t)nh * 1048576;

    // ---- stage K with rotary + roll into swizzled layout ----
#pragma unroll
    for (int it = 0; it < 4; ++it) {
        int item = it * 256 + tid;
        int ko = item >> 2, c8 = item & 3;
        int roll = ko >> 7, n = ko & 127;
        int h = (gh * 8 + (n >> 4) + (roll ? 60 : 4)) & 63;  // roll0:+4, roll1:-4 (mod 64)
        int w = gw * 16 + (n & 15);
        int row = (b * 64 + h) * 64 + w;
        bf16x8 v = *(const bf16x8*)(kkp + (size_t)row * 32 + c8 * 8);
        int pidx = (g * 256 + ko) * 16 + c8 * 4;
        float4 c4 = *(const float4*)(pekv + pidx);
        float4 s4 = *(const float4*)(pekv + 131072 + pidx);
        float cs[4] = {c4.x, c4.y, c4.z, c4.w}, sn[4] = {s4.x, s4.y, s4.z, s4.w};
        bf16x4 lo, hi;
#pragma unroll
        for (int j = 0; j < 4; ++j) {
            float k0 = (float)v[2 * j], k1 = (float)v[2 * j + 1];
            lo[j] = (__bf16)(k0 * cs[j] - k1 * sn[j]);
            hi[j] = (__bf16)(k1 * cs[j] + k0 * sn[j]);
        }
        int sw = (ko >> 1) & 3;
        int base = ko * 32, off = (c8 & 1) * 4;
        *(bf16x4*)&Ks[base + (((c8 >> 1) ^ sw) << 3) + off]       = lo;
        *(bf16x4*)&Ks[base + (((2 + (c8 >> 1)) ^ sw) << 3) + off] = hi;
    }
    // ---- stage V transposed (Vt[ch][key]) ----
#pragma unroll
    for (int it = 0; it < 4; ++it) {
        int ko = tid;
        int roll = ko >> 7, n = ko & 127;
        int h = (gh * 8 + (n >> 4) + (roll ? 60 : 4)) & 63;
        int w = gw * 16 + (n & 15);
        int row = (b * 64 + h) * 64 + w;
        bf16x8 v = *(const bf16x8*)(vvp + (size_t)row * 32 + it * 8);
#pragma unroll
        for (int j = 0; j < 8; ++j)
            Vt[(it * 8 + j) * 264 + ko] = v[j];
    }

    // ---- Q A-fragments straight into registers (overlaps staging latency) ----
    bf16x8 aq[2];
    {
        const int halfsel = quad & 1;      // raw channel half
        const bool hi_half = quad >= 2;    // rotary output half
#pragma unroll
        for (int rt = 0; rt < 2; ++rt) {
            int n = wv * 32 + rt * 16 + l16;
            int h = gh * 8 + (n >> 4), w = gw * 16 + (n & 15);
            int row = (b * 64 + h) * 64 + w;
            const __bf16* qp = qq + (size_t)row * 32 + halfsel * 16;
            bf16x8 rA = *(const bf16x8*)qp;
            bf16x8 rB = *(const bf16x8*)(qp + 8);
            int pb = (g * 128 + n) * 16 + halfsel * 8;
            float4 ca = *(const float4*)(peq + pb);
            float4 cb = *(const float4*)(peq + pb + 4);
            float4 sa = *(const float4*)(peq + 65536 + pb);
            float4 sb = *(const float4*)(peq + 65536 + pb + 4);
            float cc[8] = {ca.x, ca.y, ca.z, ca.w, cb.x, cb.y, cb.z, cb.w};
            float ss[8] = {sa.x, sa.y, sa.z, sa.w, sb.x, sb.y, sb.z, sb.w};
#pragma unroll
            for (int j = 0; j < 8; ++j) {
                float q0 = (float)(j < 4 ? rA[2 * j] : rB[2 * (j - 4)]);
                float q1 = (float)(j < 4 ? rA[2 * j + 1] : rB[2 * (j - 4) + 1]);
                float r = hi_half ? (q1 * cc[j] + q0 * ss[j]) : (q0 * cc[j] - q1 * ss[j]);
                aq[rt][j] = (__bf16)(r * ATT_SCALE);
            }
        }
    }
    __syncthreads();  // the ONLY barrier

    // ---- barrier-free flash loop: 8 chunks x 32 keys ----
    f32x4 o00 = {}, o01 = {}, o10 = {}, o11 = {};
    f32x4 rs0 = {}, rs1 = {};
    const bool use_mask = mflags[g] != 0;
    const float* mg = mask + (size_t)g * 32768;
    __bf16* Pw = Ps + wv * 640;           // private [16][40] slice
    const int arow = l16 * 40 + quad * 8; // A-frag read address (elems)

#pragma unroll 2
    for (int ch = 0; ch < 8; ++ch) {
        bf16x8 vb0 = *(const bf16x8*)&Vt[l16 * 264 + ch * 32 + quad * 8];
        bf16x8 vb1 = *(const bf16x8*)&Vt[(16 + l16) * 264 + ch * 32 + quad * 8];
        f32x4 z = {0.f, 0.f, 0.f, 0.f};
        int key0 = ch * 32 + l16, key1 = key0 + 16;
        bf16x8 bk0 = *(const bf16x8*)&Ks[key0 * 32 + ((quad ^ ((key0 >> 1) & 3)) << 3)];
        bf16x8 bk1 = *(const bf16x8*)&Ks[key1 * 32 + ((quad ^ ((key1 >> 1) & 3)) << 3)];
        f32x4 s00 = mfma16(aq[0], bk0, z), s01 = mfma16(aq[0], bk1, z);
        f32x4 s10 = mfma16(aq[1], bk0, z), s11 = mfma16(aq[1], bk1, z);

        if (use_mask) {
#pragma unroll
            for (int r = 0; r < 4; ++r) {
                int r0 = (wv * 32 + quad * 4 + r) * 256 + ch * 32 + l16;
                int r1 = (wv * 32 + 16 + quad * 4 + r) * 256 + ch * 32 + l16;
                s00[r] += mg[r0];      s01[r] += mg[r0 + 16];
                s10[r] += mg[r1];      s11[r] += mg[r1 + 16];
            }
        }
#pragma unroll
        for (int r = 0; r < 4; ++r) {
            s00[r] = __expf(s00[r]); s01[r] = __expf(s01[r]);
            s10[r] = __expf(s10[r]); s11[r] = __expf(s11[r]);
            rs0[r] += s00[r] + s01[r];
            rs1[r] += s10[r] + s11[r];
        }
        // P(rt0) -> own slice -> A-frag; in-order per-wave DS pipe makes this safe
#pragma unroll
        for (int r = 0; r < 4; ++r) {
            Pw[(quad * 4 + r) * 40 + l16]      = (__bf16)s00[r];
            Pw[(quad * 4 + r) * 40 + 16 + l16] = (__bf16)s01[r];
        }
        LDS_FENCE();
        bf16x8 a0 = *(const bf16x8*)&Pw[arow];
        LDS_FENCE();
#pragma unroll
        for (int r = 0; r < 4; ++r) {
            Pw[(quad * 4 + r) * 40 + l16]      = (__bf16)s10[r];
            Pw[(quad * 4 + r) * 40 + 16 + l16] = (__bf16)s11[r];
        }
        LDS_FENCE();
        bf16x8 a1 = *(const bf16x8*)&Pw[arow];
        LDS_FENCE();
        o00 = mfma16(a0, vb0, o00); o01 = mfma16(a0, vb1, o01);
        o10 = mfma16(a1, vb0, o10); o11 = mfma16(a1, vb1, o11);
    }

    // ---- finish row sums (16-lane butterfly) and normalize ----
#pragma unroll
    for (int off = 1; off < 16; off <<= 1) {
#pragma unroll
        for (int r = 0; r < 4; ++r) {
            rs0[r] += __shfl_xor(rs0[r], off);
            rs1[r] += __shfl_xor(rs1[r], off);
        }
    }
#pragma unroll
    for (int r = 0; r < 4; ++r) { rs0[r] = 1.f / rs0[r]; rs1[r] = 1.f / rs1[r]; }

    // ---- write O straight into (b,h,w, nh*32+c) layout (bf16) ----
#pragma unroll
    for (int r = 0; r < 4; ++r) {
        {
            int rown = wv * 32 + quad * 4 + r;
            int h = gh * 8 + (rown >> 4), w = gw * 16 + (rown & 15);
            size_t base = ((size_t)(b * 64 + h) * 64 + w) * 512 + nh * 32;
            oatt[base + l16]      = (__bf16)(o00[r] * rs0[r]);
            oatt[base + 16 + l16] = (__bf16)(o01[r] * rs0[r]);
        }
        {
            int rown = wv * 32 + 16 + quad * 4 + r;
            int h = gh * 8 + (rown >> 4), w = gw * 16 + (rown & 15);
            size_t base = ((size_t)(b * 64 + h) * 64 + w) * 512 + nh * 32;
            oatt[base + l16]      = (__bf16)(o10[r] * rs1[r]);
            oatt[base + 16 + l16] = (__bf16)(o11[r] * rs1[r]);
        }
    }
}

extern "C" void kernel_launch(void* const* d_in, const int* in_sizes, int n_in,
                              void* d_out, int out_size, void* d_ws, size_t ws_size,
                              hipStream_t stream) {
    const float* x     = (const float*)d_in[0];
    const float* peq   = (const float*)d_in[1];
    const float* pekv  = (const float*)d_in[2];
    const float* mask  = (const float*)d_in[3];
    const float* wq    = (const float*)d_in[4];
    const float* bq    = (const float*)d_in[5];
    const float* wkv   = (const float*)d_in[6];
    const float* bkv   = (const float*)d_in[7];
    const float* wproj = (const float*)d_in[8];
    const float* bproj = (const float*)d_in[9];
    float* out = (float*)d_out;

    char* ws = (char*)d_ws;
    // workspace layout (bytes):
    //   [0, 33554432)            xb (bf16 32768x512)  -- reused as o_attn after GEMM1
    //   [33554432, 35127296)     wqkvT (bf16 1536x512) -- reused as mask flags after GEMM1
    //   [35127296, 35651584)     wpT   (bf16 512x512)
    //   [35651584, 136314880)    qkv   (bf16 [3][16][32768][32])
    __bf16* xb    = (__bf16*)(ws);
    __bf16* oatt  = (__bf16*)(ws);
    __bf16* wqkvT = (__bf16*)(ws + 33554432);
    int*    mflag = (int*)(ws + 33554432);
    __bf16* wpT   = (__bf16*)(ws + 35127296);
    __bf16* qkv   = (__bf16*)(ws + 35651584);

    cast_x_kernel<<<8192, 256, 0, stream>>>((const float4*)x, (bf16x8*)xb);
    transpose_cast_kernel<<<dim3(16, 16), dim3(32, 8), 0, stream>>>(wq, wqkvT, 512, 512);
    transpose_cast_kernel<<<dim3(32, 16), dim3(32, 8), 0, stream>>>(wkv, wqkvT + 512 * 512, 512, 1024);
    transpose_cast_kernel<<<dim3(16, 16), dim3(32, 8), 0, stream>>>(wproj, wpT, 512, 512);

    gemm_bt<<<dim3(256, 12), 256, 0, stream>>>(xb, wqkvT, bq, bkv, qkv, 1536, 0);
    mask_flag_kernel<<<32, 256, 0, stream>>>(mask, mflag);
    attn_kernel<<<4096, 256, 0, stream>>>(qkv, peq, pekv, mask, mflag, oatt);
    gemm_bt<<<dim3(256, 4), 256, 0, stream>>>(oatt, wpT, bproj, bproj, out, 512, 1);
}